// Round 5
// baseline (310.602 us; speedup 1.0000x reference)
//
#include <hip/hip_runtime.h>

#define IMG    512
#define TW     32
#define TH     48
#define R      5
#define KW     11
#define HB_H   (TH + 2*R)            // 58
#define W4     33                    // hb4 padded row stride (float4 cells)
#define W1     36                    // hb1 padded row stride (floats)
#define GX     (IMG / TW)            // 16
#define GY     ((IMG + TH - 1) / TH) // 11 (last tile rows 480..527, 32 valid)
#define NBATCH 32
#define NBLOCKS (GX * GY * NBATCH)   // 5632
#define NSLOTS  64
#define PERSLOT (NBLOCKS / NSLOTS)   // 88 exactly
#define C1f 0.0001f
#define C2f 0.0009f

// ws layout (floats): slot i sum at ws[32*i] (own 128B line), slot counter at
// uint ws[32*i+1]; global slots-done counter at uint ws[32*NSLOTS]. ~8.2 KB.

// LDS = 58*33*16 + 58*36*4 + 16 = 38,992 B -> 4 blocks/CU
__global__ __launch_bounds__(256, 4) void ssim_fused_kernel(
    const float* __restrict__ x, const float* __restrict__ y,
    float* __restrict__ out, float* __restrict__ ws)
{
    __shared__ float4 hb4[HB_H][W4];  // (mu_x, mu_y, E[xx], E[yy]) horiz-filtered
    __shared__ float  hb1[HB_H][W1];  // E[xy] horiz-filtered
    __shared__ float  red[4];

    // normalized 1D Gaussian, sigma=1.5, k=11 (literals; ~1e-7 vs expf path)
    const float W[KW] = {
        0.00102838f, 0.00759874f, 0.03600077f, 0.10936075f, 0.21300553f,
        0.26601172f,
        0.21300553f, 0.10936075f, 0.03600077f, 0.00759874f, 0.00102838f};

    const int tc = blockIdx.x, tr = blockIdx.y, b = blockIdx.z;
    const int tid = threadIdx.x;
    const size_t imgBase = (size_t)b * (IMG * IMG);
    const int gr0 = tr * TH - R;
    const bool colEdge = (tc == 0) || (tc == GX - 1);

    // ========== horizontal pass: 4-px items, strided ==========
    for (int it = tid; it < HB_H * 8; it += 256) {
        const int rr = it >> 3;          // staged row 0..57
        const int g  = it & 7;           // 4-px group in row
        const int gr = gr0 + rr;
        const bool rowok = (unsigned)gr < (unsigned)IMG;
        if (!rowok) {
            const float4 z = make_float4(0.f, 0.f, 0.f, 0.f);
#pragma unroll
            for (int k = 0; k < 4; ++k) {
                hb4[rr][4*g + k] = z;
                hb1[rr][4*g + k] = 0.f;
            }
            continue;
        }
        const float4* rx = (const float4*)(x + imgBase + (size_t)gr * IMG);
        const float4* ry = (const float4*)(y + imgBase + (size_t)gr * IMG);
        const int c4 = tc * 8 + g - 2;   // first float4; taps use floats f[3..16]
        float fx[20], fy[20];
        if (colEdge) {
#pragma unroll
            for (int i = 0; i < 5; ++i) {
                int q = c4 + i;
                int qc = min(max(q, 0), IMG / 4 - 1);
                float4 vx = rx[qc], vy = ry[qc];
                float m = (q == qc) ? 1.f : 0.f;
                fx[4*i+0]=vx.x*m; fx[4*i+1]=vx.y*m; fx[4*i+2]=vx.z*m; fx[4*i+3]=vx.w*m;
                fy[4*i+0]=vy.x*m; fy[4*i+1]=vy.y*m; fy[4*i+2]=vy.z*m; fy[4*i+3]=vy.w*m;
            }
        } else {
#pragma unroll
            for (int i = 0; i < 5; ++i) {
                float4 vx = rx[c4 + i], vy = ry[c4 + i];
                fx[4*i+0]=vx.x; fx[4*i+1]=vx.y; fx[4*i+2]=vx.z; fx[4*i+3]=vx.w;
                fy[4*i+0]=vy.x; fy[4*i+1]=vy.y; fy[4*i+2]=vy.z; fy[4*i+3]=vy.w;
            }
        }
        float xx[14], yy[14], xy[14];
#pragma unroll
        for (int t = 0; t < 14; ++t) {
            float px = fx[3 + t], py = fy[3 + t];
            xx[t] = px * px; yy[t] = py * py; xy[t] = px * py;
        }
#pragma unroll
        for (int k = 0; k < 4; ++k) {
            float a0 = 0.f, a1 = 0.f, a2 = 0.f, a3 = 0.f, a4 = 0.f;
#pragma unroll
            for (int t = 0; t < KW; ++t) {
                const float wt = W[t];
                const int j = k + t;
                a0 += wt * fx[3 + j];
                a1 += wt * fy[3 + j];
                a2 += wt * xx[j];
                a3 += wt * yy[j];
                a4 += wt * xy[j];
            }
            hb4[rr][4*g + k] = make_float4(a0, a1, a2, a3);
            hb1[rr][4*g + k] = a4;
        }
    }
    __syncthreads();

    // ========== vertical pass + SSIM epilogue: 6 rows/thread ==========
    const int tx = tid & 31;
    const int ty = tid >> 5;
    const int r0 = ty * 6;

    float a0[6], a1[6], a2[6], a3[6], a4[6];
#pragma unroll
    for (int k = 0; k < 6; ++k) { a0[k]=0.f; a1[k]=0.f; a2[k]=0.f; a3[k]=0.f; a4[k]=0.f; }

#pragma unroll
    for (int t = 0; t < 16; ++t) {       // tap rows r0 .. r0+15
        float4 v4 = hb4[r0 + t][tx];
        float  v1 = hb1[r0 + t][tx];
#pragma unroll
        for (int k = 0; k < 6; ++k) {
            const int u = t - k;
            if (u >= 0 && u < KW) {      // constant-folds under full unroll
                const float wt = W[u];
                a0[k] += wt * v4.x;
                a1[k] += wt * v4.y;
                a2[k] += wt * v4.z;
                a3[k] += wt * v4.w;
                a4[k] += wt * v1;
            }
        }
    }

    float lsum = 0.f;
    const int grOut = tr * TH + r0;
#pragma unroll
    for (int k = 0; k < 6; ++k) {
        float mux = a0[k], muy = a1[k];
        float sxx = a2[k] - mux * mux;
        float syy = a3[k] - muy * muy;
        float sxy = a4[k] - mux * muy;
        float num = (2.f * mux * muy + C1f) * (2.f * sxy + C2f);
        float den = (mux * mux + muy * muy + C1f) * (sxx + syy + C2f);
        float ssim = num / (den + 1e-12f);
        ssim = fminf(fmaxf(ssim, -1.f + 1e-6f), 1.f - 1e-6f);
        lsum += (grOut + k < IMG) ? ssim : 0.f;
    }

    // ========== block reduction + distributed-atomic finalize ==========
#pragma unroll
    for (int off = 32; off > 0; off >>= 1)
        lsum += __shfl_down(lsum, off, 64);
    if ((tid & 63) == 0) red[tid >> 6] = lsum;
    __syncthreads();
    if (tid == 0) {
        const float s = red[0] + red[1] + red[2] + red[3];
        const int fid  = ((b * GY) + tr) * GX + tc;
        const int slot = fid & (NSLOTS - 1);
        float*    sumAddr = ws + 32 * slot;
        unsigned* cntAddr = (unsigned*)ws + 32 * slot + 1;
        atomicAdd(sumAddr, s);
        __threadfence();                          // my sum visible before count
        unsigned prev = atomicAdd(cntAddr, 1u);
        if (prev == (unsigned)(PERSLOT - 1)) {    // last block of this slot
            __threadfence();
            unsigned ps = atomicAdd((unsigned*)ws + 32 * NSLOTS, 1u);
            if (ps == (unsigned)(NSLOTS - 1)) {   // last slot globally
                __threadfence();
                float tot = 0.f;
#pragma unroll 4
                for (int i = 0; i < NSLOTS; ++i)
                    tot += atomicAdd(ws + 32 * i, 0.0f);  // coherent reads
                out[0] = 1.0f - tot * (1.0f / (32.0f * 512.0f * 512.0f));
            }
        }
    }
}

extern "C" void kernel_launch(void* const* d_in, const int* in_sizes, int n_in,
                              void* d_out, int out_size, void* d_ws, size_t ws_size,
                              hipStream_t stream) {
    const float* x = (const float*)d_in[0];
    const float* y = (const float*)d_in[1];
    float* out = (float*)d_out;
    float* ws  = (float*)d_ws;

    // zero 64 slot lines + global counter line: (32*64 + 32) floats = 8.25 KB
    hipMemsetAsync(d_ws, 0, (32 * NSLOTS + 32) * sizeof(float), stream);
    dim3 grid(GX, GY, NBATCH);
    ssim_fused_kernel<<<grid, 256, 0, stream>>>(x, y, out, ws);
}

// Round 6
// 203.404 us; speedup vs baseline: 1.5270x; 1.5270x over previous
//
#include <hip/hip_runtime.h>

#define IMG    512
#define TW     32
#define TH     32
#define R      5
#define KW     11
#define HB_H   (TH + 2*R)            // 42
#define W4     33                    // hb4 padded row stride (float4 cells)
#define W1     36                    // hb1 padded row stride (floats)
#define GX     (IMG / TW)            // 16
#define GY     (IMG / TH)            // 16
#define NBATCH 32
#define NBLOCKS (GX * GY * NBATCH)   // 8192
#define NSLOTS  64
#define PERSLOT (NBLOCKS / NSLOTS)   // 128
#define C1f 0.0001f
#define C2f 0.0009f

// Fixed-point packed-atomic reduction (NO fences — data rides in the atomic):
//   per-block v = llrintf(s * 2^24), |v| < 2^35
//   slot word: count in bits >=45, (v + 2^36) in bits <45 (128 adds < 2^44)
//   global word: count in bits >=50, (slot_total + 2^43) in bits <50
#define SCALEF    16777216.0f        // 2^24
#define SSHIFT    45
#define BIAS1     (1ll << 36)
#define GSHIFT    50
#define BIAS2     (1ll << 43)

// ws layout: slot i packed u64 at 128B line i (16 u64 stride); global packed
// u64 at line NSLOTS. memset zeroes (NSLOTS+1)*128 bytes.

// LDS = 42*33*16 + 42*36*4 + 16 = 28,240 B -> 5 blocks/CU (20 waves, 62%)
__global__ __launch_bounds__(256, 5) void ssim_fused_kernel(
    const float* __restrict__ x, const float* __restrict__ y,
    float* __restrict__ out, unsigned long long* __restrict__ ws)
{
    __shared__ float4 hb4[HB_H][W4];  // (mu_x, mu_y, E[xx], E[yy]) horiz-filtered
    __shared__ float  hb1[HB_H][W1];  // E[xy] horiz-filtered
    __shared__ float  red[4];

    // normalized 1D Gaussian, sigma=1.5, k=11 (literals; ~1e-7 vs expf path)
    const float W[KW] = {
        0.00102838f, 0.00759874f, 0.03600077f, 0.10936075f, 0.21300553f,
        0.26601172f,
        0.21300553f, 0.10936075f, 0.03600077f, 0.00759874f, 0.00102838f};

    const int tc = blockIdx.x, tr = blockIdx.y, b = blockIdx.z;
    const int tid = threadIdx.x;
    const size_t imgBase = (size_t)b * (IMG * IMG);
    const int gr0 = tr * TH - R;
    const bool colEdge = (tc == 0) || (tc == GX - 1);

    // ========== horizontal pass: 4-px items, strided (proven R2 body) ==========
    for (int it = tid; it < HB_H * 8; it += 256) {
        const int rr = it >> 3;          // staged row 0..41
        const int g  = it & 7;           // 4-px group in row
        const int gr = gr0 + rr;
        const bool rowok = (unsigned)gr < (unsigned)IMG;
        if (!rowok) {
            const float4 z = make_float4(0.f, 0.f, 0.f, 0.f);
#pragma unroll
            for (int k = 0; k < 4; ++k) {
                hb4[rr][4*g + k] = z;
                hb1[rr][4*g + k] = 0.f;
            }
            continue;
        }
        const float4* rx = (const float4*)(x + imgBase + (size_t)gr * IMG);
        const float4* ry = (const float4*)(y + imgBase + (size_t)gr * IMG);
        const int c4 = tc * 8 + g - 2;   // first float4; taps use floats f[3..16]
        float fx[20], fy[20];
        if (colEdge) {
#pragma unroll
            for (int i = 0; i < 5; ++i) {
                int q = c4 + i;
                int qc = min(max(q, 0), IMG / 4 - 1);
                float4 vx = rx[qc], vy = ry[qc];
                float m = (q == qc) ? 1.f : 0.f;
                fx[4*i+0]=vx.x*m; fx[4*i+1]=vx.y*m; fx[4*i+2]=vx.z*m; fx[4*i+3]=vx.w*m;
                fy[4*i+0]=vy.x*m; fy[4*i+1]=vy.y*m; fy[4*i+2]=vy.z*m; fy[4*i+3]=vy.w*m;
            }
        } else {
#pragma unroll
            for (int i = 0; i < 5; ++i) {
                float4 vx = rx[c4 + i], vy = ry[c4 + i];
                fx[4*i+0]=vx.x; fx[4*i+1]=vx.y; fx[4*i+2]=vx.z; fx[4*i+3]=vx.w;
                fy[4*i+0]=vy.x; fy[4*i+1]=vy.y; fy[4*i+2]=vy.z; fy[4*i+3]=vy.w;
            }
        }
        float xx[14], yy[14], xy[14];
#pragma unroll
        for (int t = 0; t < 14; ++t) {
            float px = fx[3 + t], py = fy[3 + t];
            xx[t] = px * px; yy[t] = py * py; xy[t] = px * py;
        }
#pragma unroll
        for (int k = 0; k < 4; ++k) {
            float a0 = 0.f, a1 = 0.f, a2 = 0.f, a3 = 0.f, a4 = 0.f;
#pragma unroll
            for (int t = 0; t < KW; ++t) {
                const float wt = W[t];
                const int j = k + t;
                a0 += wt * fx[3 + j];
                a1 += wt * fy[3 + j];
                a2 += wt * xx[j];
                a3 += wt * yy[j];
                a4 += wt * xy[j];
            }
            hb4[rr][4*g + k] = make_float4(a0, a1, a2, a3);
            hb1[rr][4*g + k] = a4;
        }
    }
    __syncthreads();

    // ========== vertical pass + SSIM epilogue: 4 rows/thread ==========
    const int tx = tid & 31;
    const int ty = tid >> 5;
    const int r0 = ty * 4;

    float a0[4], a1[4], a2[4], a3[4], a4[4];
#pragma unroll
    for (int k = 0; k < 4; ++k) { a0[k]=0.f; a1[k]=0.f; a2[k]=0.f; a3[k]=0.f; a4[k]=0.f; }

#pragma unroll
    for (int t = 0; t < 14; ++t) {       // tap rows r0 .. r0+13
        float4 v4 = hb4[r0 + t][tx];
        float  v1 = hb1[r0 + t][tx];
#pragma unroll
        for (int k = 0; k < 4; ++k) {
            const int u = t - k;
            if (u >= 0 && u < KW) {      // constant-folds under full unroll
                const float wt = W[u];
                a0[k] += wt * v4.x;
                a1[k] += wt * v4.y;
                a2[k] += wt * v4.z;
                a3[k] += wt * v4.w;
                a4[k] += wt * v1;
            }
        }
    }

    float lsum = 0.f;
#pragma unroll
    for (int k = 0; k < 4; ++k) {
        float mux = a0[k], muy = a1[k];
        float sxx = a2[k] - mux * mux;
        float syy = a3[k] - muy * muy;
        float sxy = a4[k] - mux * muy;
        float num = (2.f * mux * muy + C1f) * (2.f * sxy + C2f);
        float den = (mux * mux + muy * muy + C1f) * (sxx + syy + C2f);
        float ssim = num / (den + 1e-12f);
        ssim = fminf(fmaxf(ssim, -1.f + 1e-6f), 1.f - 1e-6f);
        lsum += ssim;
    }

    // ========== block reduction + fence-free packed-atomic finalize ==========
#pragma unroll
    for (int off = 32; off > 0; off >>= 1)
        lsum += __shfl_down(lsum, off, 64);
    if ((tid & 63) == 0) red[tid >> 6] = lsum;
    __syncthreads();
    if (tid == 0) {
        const float s = red[0] + red[1] + red[2] + red[3];
        const int fid  = ((b * GY) + tr) * GX + tc;
        const int slot = fid & (NSLOTS - 1);

        const long long v = (long long)llrintf(s * SCALEF);   // |v| < 2^35
        const unsigned long long sAdd =
            (1ull << SSHIFT) | (unsigned long long)(v + BIAS1);
        unsigned long long old = atomicAdd(&ws[16 * slot], sAdd);
        if ((old >> SSHIFT) == (unsigned long long)(PERSLOT - 1)) {
            // I completed this slot; snapshot = old + my contribution
            const long long slotSum =
                (long long)((old & ((1ull << SSHIFT) - 1)) +
                            (unsigned long long)(v + BIAS1))
                - (long long)PERSLOT * BIAS1;                  // |.| < 2^42
            const unsigned long long gAdd =
                (1ull << GSHIFT) | (unsigned long long)(slotSum + BIAS2);
            unsigned long long gold = atomicAdd(&ws[16 * NSLOTS], gAdd);
            if ((gold >> GSHIFT) == (unsigned long long)(NSLOTS - 1)) {
                const long long total =
                    (long long)((gold & ((1ull << GSHIFT) - 1)) +
                                (unsigned long long)(slotSum + BIAS2))
                    - (long long)NSLOTS * BIAS2;
                const double mean =
                    (double)total / ((double)SCALEF * (double)(NBLOCKS) * (double)(TW * TH));
                out[0] = (float)(1.0 - mean);
            }
        }
    }
}

extern "C" void kernel_launch(void* const* d_in, const int* in_sizes, int n_in,
                              void* d_out, int out_size, void* d_ws, size_t ws_size,
                              hipStream_t stream) {
    const float* x = (const float*)d_in[0];
    const float* y = (const float*)d_in[1];
    float* out = (float*)d_out;
    unsigned long long* ws = (unsigned long long*)d_ws;

    // zero NSLOTS slot lines + 1 global line (128 B each)
    hipMemsetAsync(d_ws, 0, (NSLOTS + 1) * 128, stream);
    dim3 grid(GX, GY, NBATCH);
    ssim_fused_kernel<<<grid, 256, 0, stream>>>(x, y, out, ws);
}

// Round 7
// 130.229 us; speedup vs baseline: 2.3850x; 1.5619x over previous
//
#include <hip/hip_runtime.h>

#define IMG    512
#define TW     32
#define TH     32
#define R      5
#define KW     11
#define HB_H   (TH + 2*R)            // 42
#define W4     33                    // hb4 padded row stride (float4 cells)
#define W1     36                    // hb1 padded row stride (floats)
#define GX     (IMG / TW)            // 16
#define GY     (IMG / TH)            // 16
#define NBATCH 32
#define NBLOCKS (GX * GY * NBATCH)   // 8192
#define NSLOTS  64
#define PERSLOT (NBLOCKS / NSLOTS)   // 128
#define C1f 0.0001f
#define C2f 0.0009f

// Fixed-point packed-atomic reduction (NO fences — data rides in the atomic):
//   per-block v = llrintf(s * 2^24), |v| < 2^35
//   slot word: count in bits >=45, (v + 2^36) in bits <45 (128 adds < 2^44)
//   global word: count in bits >=50, (slot_total + 2^43) in bits <50
#define SCALEF    16777216.0f        // 2^24
#define SSHIFT    45
#define BIAS1     (1ll << 36)
#define GSHIFT    50
#define BIAS2     (1ll << 43)

// ws layout: slot i packed u64 at 128B line i (16 u64 stride); global packed
// u64 at line NSLOTS. memset zeroes (NSLOTS+1)*128 bytes.

// LDS = 42*33*16 + 42*36*4 + 16 = 28,240 B -> 5 blocks/CU (LDS-limited).
// min-waves arg = 4 (VGPR cap 128): R6's ",5" squeezed VGPR to 48 and spilled
// ~128 B/thread to scratch (WRITE_SIZE 262 MB). Keep >=64 VGPR available.
__global__ __launch_bounds__(256, 4) void ssim_fused_kernel(
    const float* __restrict__ x, const float* __restrict__ y,
    float* __restrict__ out, unsigned long long* __restrict__ ws)
{
    __shared__ float4 hb4[HB_H][W4];  // (mu_x, mu_y, E[xx], E[yy]) horiz-filtered
    __shared__ float  hb1[HB_H][W1];  // E[xy] horiz-filtered
    __shared__ float  red[4];

    // normalized 1D Gaussian, sigma=1.5, k=11 (literals; ~1e-7 vs expf path)
    const float W[KW] = {
        0.00102838f, 0.00759874f, 0.03600077f, 0.10936075f, 0.21300553f,
        0.26601172f,
        0.21300553f, 0.10936075f, 0.03600077f, 0.00759874f, 0.00102838f};

    const int tc = blockIdx.x, tr = blockIdx.y, b = blockIdx.z;
    const int tid = threadIdx.x;
    const size_t imgBase = (size_t)b * (IMG * IMG);
    const int gr0 = tr * TH - R;
    const bool colEdge = (tc == 0) || (tc == GX - 1);

    // ========== horizontal pass: 4-px items, strided (proven R2 body) ==========
    for (int it = tid; it < HB_H * 8; it += 256) {
        const int rr = it >> 3;          // staged row 0..41
        const int g  = it & 7;           // 4-px group in row
        const int gr = gr0 + rr;
        const bool rowok = (unsigned)gr < (unsigned)IMG;
        if (!rowok) {
            const float4 z = make_float4(0.f, 0.f, 0.f, 0.f);
#pragma unroll
            for (int k = 0; k < 4; ++k) {
                hb4[rr][4*g + k] = z;
                hb1[rr][4*g + k] = 0.f;
            }
            continue;
        }
        const float4* rx = (const float4*)(x + imgBase + (size_t)gr * IMG);
        const float4* ry = (const float4*)(y + imgBase + (size_t)gr * IMG);
        const int c4 = tc * 8 + g - 2;   // first float4; taps use floats f[3..16]
        float fx[20], fy[20];
        if (colEdge) {
#pragma unroll
            for (int i = 0; i < 5; ++i) {
                int q = c4 + i;
                int qc = min(max(q, 0), IMG / 4 - 1);
                float4 vx = rx[qc], vy = ry[qc];
                float m = (q == qc) ? 1.f : 0.f;
                fx[4*i+0]=vx.x*m; fx[4*i+1]=vx.y*m; fx[4*i+2]=vx.z*m; fx[4*i+3]=vx.w*m;
                fy[4*i+0]=vy.x*m; fy[4*i+1]=vy.y*m; fy[4*i+2]=vy.z*m; fy[4*i+3]=vy.w*m;
            }
        } else {
#pragma unroll
            for (int i = 0; i < 5; ++i) {
                float4 vx = rx[c4 + i], vy = ry[c4 + i];
                fx[4*i+0]=vx.x; fx[4*i+1]=vx.y; fx[4*i+2]=vx.z; fx[4*i+3]=vx.w;
                fy[4*i+0]=vy.x; fy[4*i+1]=vy.y; fy[4*i+2]=vy.z; fy[4*i+3]=vy.w;
            }
        }
        float xx[14], yy[14], xy[14];
#pragma unroll
        for (int t = 0; t < 14; ++t) {
            float px = fx[3 + t], py = fy[3 + t];
            xx[t] = px * px; yy[t] = py * py; xy[t] = px * py;
        }
#pragma unroll
        for (int k = 0; k < 4; ++k) {
            float a0 = 0.f, a1 = 0.f, a2 = 0.f, a3 = 0.f, a4 = 0.f;
#pragma unroll
            for (int t = 0; t < KW; ++t) {
                const float wt = W[t];
                const int j = k + t;
                a0 += wt * fx[3 + j];
                a1 += wt * fy[3 + j];
                a2 += wt * xx[j];
                a3 += wt * yy[j];
                a4 += wt * xy[j];
            }
            hb4[rr][4*g + k] = make_float4(a0, a1, a2, a3);
            hb1[rr][4*g + k] = a4;
        }
    }
    __syncthreads();

    // ========== vertical pass + SSIM epilogue: 4 rows/thread ==========
    const int tx = tid & 31;
    const int ty = tid >> 5;
    const int r0 = ty * 4;

    float a0[4], a1[4], a2[4], a3[4], a4[4];
#pragma unroll
    for (int k = 0; k < 4; ++k) { a0[k]=0.f; a1[k]=0.f; a2[k]=0.f; a3[k]=0.f; a4[k]=0.f; }

#pragma unroll
    for (int t = 0; t < 14; ++t) {       // tap rows r0 .. r0+13
        float4 v4 = hb4[r0 + t][tx];
        float  v1 = hb1[r0 + t][tx];
#pragma unroll
        for (int k = 0; k < 4; ++k) {
            const int u = t - k;
            if (u >= 0 && u < KW) {      // constant-folds under full unroll
                const float wt = W[u];
                a0[k] += wt * v4.x;
                a1[k] += wt * v4.y;
                a2[k] += wt * v4.z;
                a3[k] += wt * v4.w;
                a4[k] += wt * v1;
            }
        }
    }

    float lsum = 0.f;
#pragma unroll
    for (int k = 0; k < 4; ++k) {
        float mux = a0[k], muy = a1[k];
        float sxx = a2[k] - mux * mux;
        float syy = a3[k] - muy * muy;
        float sxy = a4[k] - mux * muy;
        float num = (2.f * mux * muy + C1f) * (2.f * sxy + C2f);
        float den = (mux * mux + muy * muy + C1f) * (sxx + syy + C2f);
        float ssim = num / (den + 1e-12f);
        ssim = fminf(fmaxf(ssim, -1.f + 1e-6f), 1.f - 1e-6f);
        lsum += ssim;
    }

    // ========== block reduction + fence-free packed-atomic finalize ==========
#pragma unroll
    for (int off = 32; off > 0; off >>= 1)
        lsum += __shfl_down(lsum, off, 64);
    if ((tid & 63) == 0) red[tid >> 6] = lsum;
    __syncthreads();
    if (tid == 0) {
        const float s = red[0] + red[1] + red[2] + red[3];
        const int fid  = ((b * GY) + tr) * GX + tc;
        const int slot = fid & (NSLOTS - 1);

        const long long v = (long long)llrintf(s * SCALEF);   // |v| < 2^35
        const unsigned long long sAdd =
            (1ull << SSHIFT) | (unsigned long long)(v + BIAS1);
        unsigned long long old = atomicAdd(&ws[16 * slot], sAdd);
        if ((old >> SSHIFT) == (unsigned long long)(PERSLOT - 1)) {
            // I completed this slot; snapshot = old + my contribution
            const long long slotSum =
                (long long)((old & ((1ull << SSHIFT) - 1)) +
                            (unsigned long long)(v + BIAS1))
                - (long long)PERSLOT * BIAS1;                  // |.| < 2^42
            const unsigned long long gAdd =
                (1ull << GSHIFT) | (unsigned long long)(slotSum + BIAS2);
            unsigned long long gold = atomicAdd(&ws[16 * NSLOTS], gAdd);
            if ((gold >> GSHIFT) == (unsigned long long)(NSLOTS - 1)) {
                const long long total =
                    (long long)((gold & ((1ull << GSHIFT) - 1)) +
                                (unsigned long long)(slotSum + BIAS2))
                    - (long long)NSLOTS * BIAS2;
                const double mean =
                    (double)total / ((double)SCALEF * (double)(NBLOCKS) * (double)(TW * TH));
                out[0] = (float)(1.0 - mean);
            }
        }
    }
}

extern "C" void kernel_launch(void* const* d_in, const int* in_sizes, int n_in,
                              void* d_out, int out_size, void* d_ws, size_t ws_size,
                              hipStream_t stream) {
    const float* x = (const float*)d_in[0];
    const float* y = (const float*)d_in[1];
    float* out = (float*)d_out;
    unsigned long long* ws = (unsigned long long*)d_ws;

    // zero NSLOTS slot lines + 1 global line (128 B each)
    hipMemsetAsync(d_ws, 0, (NSLOTS + 1) * 128, stream);
    dim3 grid(GX, GY, NBATCH);
    ssim_fused_kernel<<<grid, 256, 0, stream>>>(x, y, out, ws);
}

// Round 8
// 128.894 us; speedup vs baseline: 2.4098x; 1.0104x over previous
//
#include <hip/hip_runtime.h>

#define IMG    512
#define TW     32
#define TH     16
#define R      5
#define KW     11
#define HB_H   (TH + 2*R)            // 26
#define W4     33                    // hb4 padded row stride (float4 cells)
#define W1     37                    // hb1 padded row stride (floats; ODD => 2-way-free writes)
#define GX     (IMG / TW)            // 16
#define GY     (IMG / TH)            // 32
#define NBATCH 32
#define NBLOCKS (GX * GY * NBATCH)   // 16384
#define NSLOTS  64
#define PERSLOT (NBLOCKS / NSLOTS)   // 256
#define C1f 0.0001f
#define C2f 0.0009f

// Fixed-point packed-atomic reduction (NO fences — data rides in the atomic):
//   per-block v = llrintf(s * 2^24), |v| <= 512*2^24 = 2^33
//   slot word: count in bits >=45; sum field holds 256*(v+2^36) <= 2^44+2^41 < 2^45
//   global word: count in bits >=50; 64*(slotSum+2^43) < 2^50
#define SCALEF    16777216.0f        // 2^24
#define SSHIFT    45
#define BIAS1     (1ll << 36)
#define GSHIFT    50
#define BIAS2     (1ll << 43)

// LDS = 26*33*16 + 26*37*4 + 16 = 17,592 B -> 8 blocks/CU if VGPR<=64
// (32 waves/CU, 100% of wave slots). R7 was 5 blocks at 28.2 KB -> latency-bound.
// launch_bounds min-waves stays 4 (VGPR cap 128): NO spill cliff (R6 lesson);
// compiler landed at 64 VGPR for the heavier R7 body, expect <=64 here.
__global__ __launch_bounds__(256, 4) void ssim_fused_kernel(
    const float* __restrict__ x, const float* __restrict__ y,
    float* __restrict__ out, unsigned long long* __restrict__ ws)
{
    __shared__ float4 hb4[HB_H][W4];  // (mu_x, mu_y, E[xx], E[yy]) horiz-filtered
    __shared__ float  hb1[HB_H][W1];  // E[xy] horiz-filtered
    __shared__ float  red[4];

    // normalized 1D Gaussian, sigma=1.5, k=11 (literals; ~1e-7 vs expf path)
    const float W[KW] = {
        0.00102838f, 0.00759874f, 0.03600077f, 0.10936075f, 0.21300553f,
        0.26601172f,
        0.21300553f, 0.10936075f, 0.03600077f, 0.00759874f, 0.00102838f};

    const int tc = blockIdx.x, tr = blockIdx.y, b = blockIdx.z;
    const int tid = threadIdx.x;
    const size_t imgBase = (size_t)b * (IMG * IMG);
    const int gr0 = tr * TH - R;
    const bool colEdge = (tc == 0) || (tc == GX - 1);

    // ========== horizontal pass: 4-px items, single trip (208 <= 256) ==========
    if (tid < HB_H * 8) {
        const int rr = tid >> 3;         // staged row 0..25
        const int g  = tid & 7;          // 4-px group in row
        const int gr = gr0 + rr;
        const bool rowok = (unsigned)gr < (unsigned)IMG;
        if (rowok) {
            const float4* rx = (const float4*)(x + imgBase + (size_t)gr * IMG);
            const float4* ry = (const float4*)(y + imgBase + (size_t)gr * IMG);
            const int c4 = tc * 8 + g - 2;   // first float4; taps use floats f[3..16]
            float fx[20], fy[20];
            if (colEdge) {
#pragma unroll
                for (int i = 0; i < 5; ++i) {
                    int q = c4 + i;
                    int qc = min(max(q, 0), IMG / 4 - 1);
                    float4 vx = rx[qc], vy = ry[qc];
                    float m = (q == qc) ? 1.f : 0.f;
                    fx[4*i+0]=vx.x*m; fx[4*i+1]=vx.y*m; fx[4*i+2]=vx.z*m; fx[4*i+3]=vx.w*m;
                    fy[4*i+0]=vy.x*m; fy[4*i+1]=vy.y*m; fy[4*i+2]=vy.z*m; fy[4*i+3]=vy.w*m;
                }
            } else {
#pragma unroll
                for (int i = 0; i < 5; ++i) {
                    float4 vx = rx[c4 + i], vy = ry[c4 + i];
                    fx[4*i+0]=vx.x; fx[4*i+1]=vx.y; fx[4*i+2]=vx.z; fx[4*i+3]=vx.w;
                    fy[4*i+0]=vy.x; fy[4*i+1]=vy.y; fy[4*i+2]=vy.z; fy[4*i+3]=vy.w;
                }
            }
            float xx[14], yy[14], xy[14];
#pragma unroll
            for (int t = 0; t < 14; ++t) {
                float px = fx[3 + t], py = fy[3 + t];
                xx[t] = px * px; yy[t] = py * py; xy[t] = px * py;
            }
#pragma unroll
            for (int k = 0; k < 4; ++k) {
                float a0 = 0.f, a1 = 0.f, a2 = 0.f, a3 = 0.f, a4 = 0.f;
#pragma unroll
                for (int t = 0; t < KW; ++t) {
                    const float wt = W[t];
                    const int j = k + t;
                    a0 += wt * fx[3 + j];
                    a1 += wt * fy[3 + j];
                    a2 += wt * xx[j];
                    a3 += wt * yy[j];
                    a4 += wt * xy[j];
                }
                hb4[rr][4*g + k] = make_float4(a0, a1, a2, a3);
                hb1[rr][4*g + k] = a4;
            }
        } else {
            const float4 z = make_float4(0.f, 0.f, 0.f, 0.f);
#pragma unroll
            for (int k = 0; k < 4; ++k) {
                hb4[rr][4*g + k] = z;
                hb1[rr][4*g + k] = 0.f;
            }
        }
    }
    __syncthreads();

    // ========== vertical pass + SSIM epilogue: 2 rows/thread ==========
    const int tx = tid & 31;
    const int ty = tid >> 5;
    const int r0 = ty * 2;

    float a0[2], a1[2], a2[2], a3[2], a4[2];
#pragma unroll
    for (int k = 0; k < 2; ++k) { a0[k]=0.f; a1[k]=0.f; a2[k]=0.f; a3[k]=0.f; a4[k]=0.f; }

#pragma unroll
    for (int t = 0; t < 12; ++t) {       // tap rows r0 .. r0+11
        float4 v4 = hb4[r0 + t][tx];
        float  v1 = hb1[r0 + t][tx];
#pragma unroll
        for (int k = 0; k < 2; ++k) {
            const int u = t - k;
            if (u >= 0 && u < KW) {      // constant-folds under full unroll
                const float wt = W[u];
                a0[k] += wt * v4.x;
                a1[k] += wt * v4.y;
                a2[k] += wt * v4.z;
                a3[k] += wt * v4.w;
                a4[k] += wt * v1;
            }
        }
    }

    float lsum = 0.f;
#pragma unroll
    for (int k = 0; k < 2; ++k) {
        float mux = a0[k], muy = a1[k];
        float sxx = a2[k] - mux * mux;
        float syy = a3[k] - muy * muy;
        float sxy = a4[k] - mux * muy;
        float num = (2.f * mux * muy + C1f) * (2.f * sxy + C2f);
        float den = (mux * mux + muy * muy + C1f) * (sxx + syy + C2f);
        float ssim = num / (den + 1e-12f);
        ssim = fminf(fmaxf(ssim, -1.f + 1e-6f), 1.f - 1e-6f);
        lsum += ssim;
    }

    // ========== block reduction + fence-free packed-atomic finalize ==========
#pragma unroll
    for (int off = 32; off > 0; off >>= 1)
        lsum += __shfl_down(lsum, off, 64);
    if ((tid & 63) == 0) red[tid >> 6] = lsum;
    __syncthreads();
    if (tid == 0) {
        const float s = red[0] + red[1] + red[2] + red[3];
        const int fid  = ((b * GY) + tr) * GX + tc;
        const int slot = fid & (NSLOTS - 1);

        const long long v = (long long)llrintf(s * SCALEF);   // |v| <= 2^33
        const unsigned long long sAdd =
            (1ull << SSHIFT) | (unsigned long long)(v + BIAS1);
        unsigned long long old = atomicAdd(&ws[16 * slot], sAdd);
        if ((old >> SSHIFT) == (unsigned long long)(PERSLOT - 1)) {
            // I completed this slot; snapshot = old + my contribution
            const long long slotSum =
                (long long)((old & ((1ull << SSHIFT) - 1)) +
                            (unsigned long long)(v + BIAS1))
                - (long long)PERSLOT * BIAS1;
            const unsigned long long gAdd =
                (1ull << GSHIFT) | (unsigned long long)(slotSum + BIAS2);
            unsigned long long gold = atomicAdd(&ws[16 * NSLOTS], gAdd);
            if ((gold >> GSHIFT) == (unsigned long long)(NSLOTS - 1)) {
                const long long total =
                    (long long)((gold & ((1ull << GSHIFT) - 1)) +
                                (unsigned long long)(slotSum + BIAS2))
                    - (long long)NSLOTS * BIAS2;
                const double mean =
                    (double)total / ((double)SCALEF * (double)NBLOCKS * (double)(TW * TH));
                out[0] = (float)(1.0 - mean);
            }
        }
    }
}

extern "C" void kernel_launch(void* const* d_in, const int* in_sizes, int n_in,
                              void* d_out, int out_size, void* d_ws, size_t ws_size,
                              hipStream_t stream) {
    const float* x = (const float*)d_in[0];
    const float* y = (const float*)d_in[1];
    float* out = (float*)d_out;
    unsigned long long* ws = (unsigned long long*)d_ws;

    // zero NSLOTS slot lines + 1 global line (128 B each)
    hipMemsetAsync(d_ws, 0, (NSLOTS + 1) * 128, stream);
    dim3 grid(GX, GY, NBATCH);
    ssim_fused_kernel<<<grid, 256, 0, stream>>>(x, y, out, ws);
}